// Round 19
// baseline (263.793 us; speedup 1.0000x reference)
//
#include <hip/hip_runtime.h>
#include <hip/hip_bf16.h>
#include <math.h>

#define N_STATIONS 276
#define CTX 384
#define TGT 96
#define BATCH 4096
#define NT_MAX 532                  // >= Σceil(m/16) worst case
#define NBLK (N_STATIONS * 6)       // 1656 = 8*207 hot tasks
#define CPX (NBLK / 8)              // 207 (bijective XCD swizzle)

// ws layout (ints):
//   [0]                  ntiles
//   [1 .. 533)           tiles packed s<<16|tt
//   [1024 .. 5120)       order
//   [5120 .. 5397)       offsets (samples)
//   [5600 .. 5877)       tileoff (global tile index base per station)
//   [8192 .. 8192+532*32) per-tile meta: {s, mrem, oids[16], ...} (32 ints)
//   [262144 .. )         zf: per-tile A-fragment buffer, 12 KB each (bf16)
#define META_OFF 8192
#define TILEOFF  5600
#define ZF_OFF   262144

typedef __attribute__((ext_vector_type(8))) short bf16x8;   // 8 bf16 (4 VGPRs)
typedef __attribute__((ext_vector_type(4))) float f32x4;    // MFMA acc

__device__ __forceinline__ short f2bf(float f) {
    return (short)__builtin_bit_cast(unsigned short, __float2bfloat16(f));
}

// ---------- kernel 1: per-station lists + tile list + tile offsets ----------
__global__ __launch_bounds__(1024) void build_lists(
    const int* __restrict__ stations, int* __restrict__ ws)
{
    __shared__ int cnt[N_STATIONS], cnt2[N_STATIONS];
    __shared__ int poff[N_STATIONS + 1], tpoff[N_STATIONS + 1];
    const int tid = threadIdx.x;
    for (int i = tid; i < N_STATIONS; i += 1024) { cnt[i] = 0; cnt2[i] = 0; }
    __syncthreads();
    for (int b = tid; b < BATCH; b += 1024) atomicAdd(&cnt[stations[b]], 1);
    __syncthreads();
    if (tid < 64) {   // dual wave-parallel inclusive scan (samples, tiles)
        int run = 0, trun = 0;
        for (int base = 0; base < N_STATIONS; base += 64) {
            const int i = base + tid;
            int c  = (i < N_STATIONS) ? cnt[i] : 0;
            int v  = c, tv = (c + 15) >> 4;
#pragma unroll
            for (int off = 1; off < 64; off <<= 1) {
                int u  = __shfl_up(v, off, 64);
                int tu = __shfl_up(tv, off, 64);
                if (tid >= off) { v += u; tv += tu; }
            }
            if (i < N_STATIONS) { poff[i + 1] = run + v; tpoff[i + 1] = trun + tv; }
            run  += __shfl(v, 63, 64);
            trun += __shfl(tv, 63, 64);
        }
        if (tid == 0) { poff[0] = 0; tpoff[0] = 0; }
    }
    __syncthreads();
    int* order = ws + 1024;
    for (int b = tid; b < BATCH; b += 1024) {
        int s = stations[b];
        int p = atomicAdd(&cnt2[s], 1);
        order[poff[s] + p] = b;          // within-station order irrelevant to outputs
    }
    for (int i = tid; i < N_STATIONS; i += 1024) {
        int n = (cnt[i] + 15) >> 4, base = tpoff[i];
        for (int t = 0; t < n; ++t) ws[1 + base + t] = (i << 16) | t;
    }
    if (tid <= N_STATIONS) ws[5120 + tid]    = poff[tid];
    if (tid <= N_STATIONS) ws[TILEOFF + tid] = tpoff[tid];
    if (tid == 0) ws[0] = tpoff[N_STATIONS];
}

// ---------- kernel 2: z-staging — gather+normalize+bf16 into A-frag layout ----------
__global__ __launch_bounds__(256) void zstage(
    const float* __restrict__ z,
    const float* __restrict__ loc,
    const float* __restrict__ scale,
    int* __restrict__ ws)
{
    const int ntiles = ws[0];
    const int tb = blockIdx.x;
    if (tb >= ntiles) return;

    const int pk = ws[1 + tb];
    const int s  = pk >> 16;
    const int tt = pk & 0xFFFF;
    const int* order   = ws + 1024;
    const int* offsets = ws + 5120;
    const int start = offsets[s];
    const int m     = offsets[s + 1] - start;

    const float lc = loc[s], inv = 1.0f / scale[s], nb = -lc * inv;

    int* rec = ws + META_OFF + tb * 32;
    const int t = threadIdx.x;
    if (t < 16) {
        int j = tt * 16 + t; if (j > m - 1) j = m - 1;
        rec[2 + t] = order[start + j];
    }
    if (t == 0) { rec[0] = s; int mr = m - tt * 16; rec[1] = mr > 16 ? 16 : mr; }

    unsigned short* zt = (unsigned short*)(ws + ZF_OFF) + (size_t)tb * 6144;
    for (int q = t; q < 768; q += 256) {
        const int kstep = q >> 6, lane = q & 63;
        const int sample = lane & 15;
        const int kb = kstep * 32 + (lane >> 4) * 8;
        int j = tt * 16 + sample; if (j > m - 1) j = m - 1;
        const float* zr = z + (size_t)order[start + j] * CTX + kb;
        float4 a0 = *(const float4*)zr;
        float4 a1 = *(const float4*)(zr + 4);
        float f[8] = {a0.x, a0.y, a0.z, a0.w, a1.x, a1.y, a1.z, a1.w};
        union { unsigned short u[8]; uint4 v; } o;
#pragma unroll
        for (int i = 0; i < 8; ++i)
            o.u[i] = (unsigned short)f2bf(fmaf(f[i], inv, nb));
        *(uint4*)(zt + (size_t)q * 8) = o.v;
    }
}

// ---------- kernel 3: hot — one wave per (station, nt); W read ONCE ----------
// Per K-step: one W fragment (cvt to bf16) feeds G<=6 MFMAs, one per sample-
// tile, with staged zf fragments (L2-hot). Accs statically indexed + guarded.
__global__ __launch_bounds__(64, 4) void nlinear_hot3(
    const float* __restrict__ W,        // (N_STATIONS, TGT, CTX)
    const float* __restrict__ bias,     // (N_STATIONS, TGT)
    const float* __restrict__ loc,
    const float* __restrict__ scale,
    const int*   __restrict__ ws,
    float*       __restrict__ out)      // (BATCH, TGT)
{
    const int b0 = blockIdx.x;
    const int b  = (b0 & 7) * CPX + (b0 >> 3);   // bijective: station's 6 nt on one XCD
    const int s  = b / 6;
    const int nt = b - 6 * s;

    const int* offsets = ws + 5120;
    const int start = offsets[s];
    const int m     = offsets[s + 1] - start;
    if (m <= 0) return;
    const int tbase  = ws[TILEOFF + s];
    const int ntiles = (m + 15) >> 4;

    const int l  = threadIdx.x;
    const int lr = l & 15;
    const int kh = (l >> 4) * 8;

    const float* wr = W + ((size_t)s * TGT + nt * 16 + lr) * CTX + kh;
    const unsigned short* ztall = (const unsigned short*)(ws + ZF_OFF);

    const float sc = scale[s], lc = loc[s];
    const float bv = bias[(size_t)s * TGT + nt * 16 + lr];
    const int rbase = (l >> 4) * 4;

    for (int tg = 0; tg < ntiles; tg += 6) {
        const int G = min(6, ntiles - tg);
        const unsigned short* zt0 = ztall + (size_t)(tbase + tg) * 6144 + (size_t)l * 8;

        f32x4 acc[6];
#pragma unroll
        for (int t = 0; t < 6; ++t) acc[t] = (f32x4){0.f, 0.f, 0.f, 0.f};

        // W pipeline: depth 2 (wc = step kk, wn = step kk+1)
        float4 wc0 = *(const float4*)(wr);
        float4 wc1 = *(const float4*)(wr + 4);
        float4 wn0 = *(const float4*)(wr + 32);
        float4 wn1 = *(const float4*)(wr + 36);

#pragma unroll
        for (int kk = 0; kk < 12; ++kk) {
            // zf fragments for this K-step, G tiles (16B each, L2-hot)
            bf16x8 za[6];
#pragma unroll
            for (int t = 0; t < 6; ++t)
                if (t < G) za[t] = *(const bf16x8*)(zt0 + (size_t)t * 6144 + (size_t)kk * 512);

            bf16x8 bh;
            bh[0] = f2bf(wc0.x); bh[1] = f2bf(wc0.y);
            bh[2] = f2bf(wc0.z); bh[3] = f2bf(wc0.w);
            bh[4] = f2bf(wc1.x); bh[5] = f2bf(wc1.y);
            bh[6] = f2bf(wc1.z); bh[7] = f2bf(wc1.w);

#pragma unroll
            for (int t = 0; t < 6; ++t)
                if (t < G) acc[t] = __builtin_amdgcn_mfma_f32_16x16x32_bf16(za[t], bh, acc[t], 0, 0, 0);

            wc0 = wn0; wc1 = wn1;
            if (kk < 10) {
                wn0 = *(const float4*)(wr + (kk + 2) * 32);
                wn1 = *(const float4*)(wr + (kk + 2) * 32 + 4);
            }
        }

        // epilogue per tile
#pragma unroll
        for (int t = 0; t < 6; ++t) {
            if (t < G) {
                const int* rec = ws + META_OFF + (tbase + tg + t) * 32;
                const int mrem = rec[1];
#pragma unroll
                for (int r = 0; r < 4; ++r) {
                    const int jj = rbase + r;
                    if (jj < mrem) {
                        const int oid = rec[2 + jj];
                        float v = (acc[t][r] + bv) * sc + lc;
                        out[(size_t)oid * TGT + nt * 16 + lr] =
                            fmaxf(v, 0.f) + log1pf(expf(-fabsf(v)));
                    }
                }
            }
        }
    }
}

extern "C" void kernel_launch(void* const* d_in, const int* in_sizes, int n_in,
                              void* d_out, int out_size, void* d_ws, size_t ws_size,
                              hipStream_t stream) {
    const float* z        = (const float*)d_in[0];
    const int*   stations = (const int*)  d_in[1];
    const float* W        = (const float*)d_in[2];
    const float* bias     = (const float*)d_in[3];
    const float* loc      = (const float*)d_in[4];
    const float* scale    = (const float*)d_in[5];
    float* out = (float*)d_out;
    int* ws = (int*)d_ws;

    build_lists<<<1, 1024, 0, stream>>>(stations, ws);
    zstage<<<NT_MAX, 256, 0, stream>>>(z, loc, scale, ws);
    nlinear_hot3<<<NBLK, 64, 0, stream>>>(W, bias, loc, scale, ws, out);
}

// Round 20
// 31.142 us; speedup vs baseline: 8.4707x; 8.4707x over previous
//
#include <hip/hip_runtime.h>
#include <hip/hip_bf16.h>
#include <math.h>

#define N_STATIONS 276
#define CTX 384
#define TGT 96
#define BATCH 4096
#define NT_MAX 532                  // >= Σceil(m/16) worst case
#define NBLK (N_STATIONS * 6)       // 1656 = 8*207 hot tasks
#define CPX (NBLK / 8)              // 207 (bijective XCD swizzle)

// ws layout (ints):
//   [0]                  ntiles
//   [1 .. 533)           tiles packed s<<16|tt
//   [1024 .. 5120)       order
//   [5120 .. 5397)       offsets (samples)
//   [5600 .. 5877)       tileoff (global tile index base per station)
//   [8192 .. 8192+532*32) per-tile meta: {s, mrem, oids[16], ...} (32 ints)
//   [262144 .. )         zf: per-tile A-fragment buffer, 12 KB each (bf16)
#define META_OFF 8192
#define TILEOFF  5600
#define ZF_OFF   262144

typedef __attribute__((ext_vector_type(8))) short bf16x8;   // 8 bf16 (4 VGPRs)
typedef __attribute__((ext_vector_type(4))) float f32x4;    // MFMA acc

__device__ __forceinline__ short f2bf(float f) {
    return (short)__builtin_bit_cast(unsigned short, __float2bfloat16(f));
}

// ---------- kernel 1: per-station lists + tile list + tile offsets ----------
__global__ __launch_bounds__(1024) void build_lists(
    const int* __restrict__ stations, int* __restrict__ ws)
{
    __shared__ int cnt[N_STATIONS], cnt2[N_STATIONS];
    __shared__ int poff[N_STATIONS + 1], tpoff[N_STATIONS + 1];
    const int tid = threadIdx.x;
    for (int i = tid; i < N_STATIONS; i += 1024) { cnt[i] = 0; cnt2[i] = 0; }
    __syncthreads();
    for (int b = tid; b < BATCH; b += 1024) atomicAdd(&cnt[stations[b]], 1);
    __syncthreads();
    if (tid < 64) {   // dual wave-parallel inclusive scan (samples, tiles)
        int run = 0, trun = 0;
        for (int base = 0; base < N_STATIONS; base += 64) {
            const int i = base + tid;
            int c  = (i < N_STATIONS) ? cnt[i] : 0;
            int v  = c, tv = (c + 15) >> 4;
#pragma unroll
            for (int off = 1; off < 64; off <<= 1) {
                int u  = __shfl_up(v, off, 64);
                int tu = __shfl_up(tv, off, 64);
                if (tid >= off) { v += u; tv += tu; }
            }
            if (i < N_STATIONS) { poff[i + 1] = run + v; tpoff[i + 1] = trun + tv; }
            run  += __shfl(v, 63, 64);
            trun += __shfl(tv, 63, 64);
        }
        if (tid == 0) { poff[0] = 0; tpoff[0] = 0; }
    }
    __syncthreads();
    int* order = ws + 1024;
    for (int b = tid; b < BATCH; b += 1024) {
        int s = stations[b];
        int p = atomicAdd(&cnt2[s], 1);
        order[poff[s] + p] = b;          // within-station order irrelevant to outputs
    }
    for (int i = tid; i < N_STATIONS; i += 1024) {
        int n = (cnt[i] + 15) >> 4, base = tpoff[i];
        for (int t = 0; t < n; ++t) ws[1 + base + t] = (i << 16) | t;
    }
    if (tid <= N_STATIONS) ws[5120 + tid]    = poff[tid];
    if (tid <= N_STATIONS) ws[TILEOFF + tid] = tpoff[tid];
    if (tid == 0) ws[0] = tpoff[N_STATIONS];
}

// ---------- kernel 2: z-staging — gather+normalize+bf16 into A-frag layout ----------
__global__ __launch_bounds__(256) void zstage(
    const float* __restrict__ z,
    const float* __restrict__ loc,
    const float* __restrict__ scale,
    int* __restrict__ ws)
{
    const int ntiles = ws[0];
    const int tb = blockIdx.x;
    if (tb >= ntiles) return;

    const int pk = ws[1 + tb];
    const int s  = pk >> 16;
    const int tt = pk & 0xFFFF;
    const int* order   = ws + 1024;
    const int* offsets = ws + 5120;
    const int start = offsets[s];
    const int m     = offsets[s + 1] - start;

    const float lc = loc[s], inv = 1.0f / scale[s], nb = -lc * inv;

    int* rec = ws + META_OFF + tb * 32;
    const int t = threadIdx.x;
    if (t < 16) {
        int j = tt * 16 + t; if (j > m - 1) j = m - 1;
        rec[2 + t] = order[start + j];
    }
    if (t == 0) { rec[0] = s; int mr = m - tt * 16; rec[1] = mr > 16 ? 16 : mr; }

    unsigned short* zt = (unsigned short*)(ws + ZF_OFF) + (size_t)tb * 6144;
    for (int q = t; q < 768; q += 256) {
        const int kstep = q >> 6, lane = q & 63;
        const int sample = lane & 15;
        const int kb = kstep * 32 + (lane >> 4) * 8;
        int j = tt * 16 + sample; if (j > m - 1) j = m - 1;
        const float* zr = z + (size_t)order[start + j] * CTX + kb;
        float4 a0 = *(const float4*)zr;
        float4 a1 = *(const float4*)(zr + 4);
        float f[8] = {a0.x, a0.y, a0.z, a0.w, a1.x, a1.y, a1.z, a1.w};
        union { unsigned short u[8]; uint4 v; } o;
#pragma unroll
        for (int i = 0; i < 8; ++i)
            o.u[i] = (unsigned short)f2bf(fmaf(f[i], inv, nb));
        *(uint4*)(zt + (size_t)q * 8) = o.v;
    }
}

// ---------- kernel 3: hot — one wave per (station, nt); W read ONCE ----------
// G=3 sample-tiles per W pass (2 passes max). NO guards in the K-loop:
// tile indices clamped (duplicate compute OK, epilogue guarded) so every
// load/MFMA issues unconditionally -> no predication, no spill.
__global__ __launch_bounds__(64, 1) void nlinear_hot3(
    const float* __restrict__ W,        // (N_STATIONS, TGT, CTX)
    const float* __restrict__ bias,     // (N_STATIONS, TGT)
    const float* __restrict__ loc,
    const float* __restrict__ scale,
    const int*   __restrict__ ws,
    float*       __restrict__ out)      // (BATCH, TGT)
{
    const int b0 = blockIdx.x;
    const int b  = (b0 & 7) * CPX + (b0 >> 3);   // bijective: station's 6 nt on one XCD
    const int s  = b / 6;
    const int nt = b - 6 * s;

    const int* offsets = ws + 5120;
    const int start = offsets[s];
    const int m     = offsets[s + 1] - start;
    if (m <= 0) return;
    const int tbase  = ws[TILEOFF + s];
    const int ntiles = (m + 15) >> 4;

    const int l  = threadIdx.x;
    const int lr = l & 15;
    const int kh = (l >> 4) * 8;

    const float* wr = W + ((size_t)s * TGT + nt * 16 + lr) * CTX + kh;
    const unsigned short* ztall = (const unsigned short*)(ws + ZF_OFF);

    const float sc = scale[s], lc = loc[s];
    const float bv = bias[(size_t)s * TGT + nt * 16 + lr];
    const int rbase = (l >> 4) * 4;

    for (int tg = 0; tg < ntiles; tg += 3) {
        // clamped tile ids -> all loads unconditional
        int ti0 = tg,     ti1 = tg + 1, ti2 = tg + 2;
        if (ti1 > ntiles - 1) ti1 = ntiles - 1;
        if (ti2 > ntiles - 1) ti2 = ntiles - 1;
        const unsigned short* zp0 = ztall + (size_t)(tbase + ti0) * 6144 + (size_t)l * 8;
        const unsigned short* zp1 = ztall + (size_t)(tbase + ti1) * 6144 + (size_t)l * 8;
        const unsigned short* zp2 = ztall + (size_t)(tbase + ti2) * 6144 + (size_t)l * 8;

        f32x4 a0 = {0.f,0.f,0.f,0.f}, a1 = {0.f,0.f,0.f,0.f}, a2 = {0.f,0.f,0.f,0.f};

        // W pipeline: depth 2
        float4 wc0 = *(const float4*)(wr);
        float4 wc1 = *(const float4*)(wr + 4);
        float4 wn0 = *(const float4*)(wr + 32);
        float4 wn1 = *(const float4*)(wr + 36);

#pragma unroll
        for (int kk = 0; kk < 12; ++kk) {
            bf16x8 z0 = *(const bf16x8*)(zp0 + (size_t)kk * 512);
            bf16x8 z1 = *(const bf16x8*)(zp1 + (size_t)kk * 512);
            bf16x8 z2 = *(const bf16x8*)(zp2 + (size_t)kk * 512);

            bf16x8 bh;
            bh[0] = f2bf(wc0.x); bh[1] = f2bf(wc0.y);
            bh[2] = f2bf(wc0.z); bh[3] = f2bf(wc0.w);
            bh[4] = f2bf(wc1.x); bh[5] = f2bf(wc1.y);
            bh[6] = f2bf(wc1.z); bh[7] = f2bf(wc1.w);

            a0 = __builtin_amdgcn_mfma_f32_16x16x32_bf16(z0, bh, a0, 0, 0, 0);
            a1 = __builtin_amdgcn_mfma_f32_16x16x32_bf16(z1, bh, a1, 0, 0, 0);
            a2 = __builtin_amdgcn_mfma_f32_16x16x32_bf16(z2, bh, a2, 0, 0, 0);

            wc0 = wn0; wc1 = wn1;
            if (kk < 10) {
                wn0 = *(const float4*)(wr + (kk + 2) * 32);
                wn1 = *(const float4*)(wr + (kk + 2) * 32 + 4);
            }
        }

        // epilogue: only real tiles store
#pragma unroll
        for (int t = 0; t < 3; ++t) {
            if (tg + t < ntiles) {
                const f32x4 av = (t == 0) ? a0 : (t == 1) ? a1 : a2;
                const int* rec = ws + META_OFF + (tbase + tg + t) * 32;
                const int mrem = rec[1];
#pragma unroll
                for (int r = 0; r < 4; ++r) {
                    const int jj = rbase + r;
                    if (jj < mrem) {
                        const int oid = rec[2 + jj];
                        float v = (av[r] + bv) * sc + lc;
                        out[(size_t)oid * TGT + nt * 16 + lr] =
                            fmaxf(v, 0.f) + log1pf(expf(-fabsf(v)));
                    }
                }
            }
        }
    }
}

extern "C" void kernel_launch(void* const* d_in, const int* in_sizes, int n_in,
                              void* d_out, int out_size, void* d_ws, size_t ws_size,
                              hipStream_t stream) {
    const float* z        = (const float*)d_in[0];
    const int*   stations = (const int*)  d_in[1];
    const float* W        = (const float*)d_in[2];
    const float* bias     = (const float*)d_in[3];
    const float* loc      = (const float*)d_in[4];
    const float* scale    = (const float*)d_in[5];
    float* out = (float*)d_out;
    int* ws = (int*)d_ws;

    build_lists<<<1, 1024, 0, stream>>>(stations, ws);
    zstage<<<NT_MAX, 256, 0, stream>>>(z, loc, scale, ws);
    nlinear_hot3<<<NBLK, 64, 0, stream>>>(W, bias, loc, scale, ws, out);
}